// Round 2
// baseline (14904.655 us; speedup 1.0000x reference)
//
#include <hip/hip_runtime.h>

typedef unsigned short u16;
typedef unsigned int u32;
typedef __bf16 bf16x8 __attribute__((ext_vector_type(8)));
typedef float f32x4 __attribute__((ext_vector_type(4)));

#define YD 32
#define ZD 64
#define HD 256
#define RD 256
#define TSTEPS 199   // T-1 scan steps
#define BB 2048
#define MROWS 64     // batch rows per block
#define NBLK 32      // 2048/64
#define NTHR 512     // 8 waves
#define CATS 392     // [x(32)|y(32)|z(64)|h(256)] = 384 + 8 pad
#define HBS  264     // 256 + 8 pad

// bf16 weight layout offsets inside d_ws (element units, (N,K) row-major, K contiguous)
enum : int {
  OFF_ENC_W1 = 0,        // 256x320
  OFF_ENC_W2 = 81920,    // 256x256
  OFF_ENC_H  = 147456,   // [enc_mw;enc_sw] 128x256
  OFF_PRI_W1 = 180224,   // 256x288
  OFF_PRI_W2 = 253952,   // 256x256
  OFF_PRI_H  = 319488,   // [pri_mw;pri_sw] 128x256
  OFF_DEC_W1 = 352256,   // 256x352
  OFF_DEC_W2 = 442368,   // 256x256
  OFF_DEC_H  = 507904,   // [dec_mw;dec_sw] 64x256
  OFF_GWIH   = 524288,   // 768x96
  OFF_GWHH   = 598016,   // 768x256
};

__device__ __forceinline__ u16 f2bf(float f) {
  u32 u = __float_as_uint(f);
  u += 0x7fffu + ((u >> 16) & 1u);   // RTNE
  return (u16)(u >> 16);
}
__device__ __forceinline__ float softplus_f(float x) {
  float l = __logf(1.f + __expf(-fabsf(x)));
  return x > 0.f ? x + l : l;
}
__device__ __forceinline__ float sigmoid_f(float x) {
  return __builtin_amdgcn_rcpf(1.f + __expf(-x));
}
__device__ __forceinline__ float tanh_f(float x) {
  float e = __expf(-2.f * fabsf(x));
  float t = (1.f - e) * __builtin_amdgcn_rcpf(1.f + e);
  return x >= 0.f ? t : -t;
}

// Wave-level GEMM over one contiguous K-segment.
// A (LDS, row-major, stride AS elems): rows (rt0+rt)*16 + (lane&15), cols acol0 + ks*32 + quad*8
// W (global bf16, (N,Kw) row-major):   rows wrow0 + nt*16 + (lane&15), cols wk0 + ks*32 + quad*8
// D[m][n] += sum_k A[m][k]*W[n][k]  (i.e. act @ W.T)
template<int NT, int RT, int KS, int AS>
__device__ __forceinline__ void gemm_seg(f32x4 (&acc)[NT][RT],
    const u16* __restrict__ W, const int Kw, const int wrow0, const int wk0,
    const u16* A, const int acol0, const int rt0, const int lane)
{
  const int n = lane & 15, quad = lane >> 4;
  #pragma unroll
  for (int ks = 0; ks < KS; ++ks) {
    bf16x8 a[RT];
    #pragma unroll
    for (int rt = 0; rt < RT; ++rt)
      a[rt] = *reinterpret_cast<const bf16x8*>(A + ((rt0 + rt) * 16 + n) * AS + acol0 + ks * 32 + quad * 8);
    #pragma unroll
    for (int nt = 0; nt < NT; ++nt) {
      bf16x8 b = *reinterpret_cast<const bf16x8*>(W + (size_t)(wrow0 + nt * 16 + n) * Kw + wk0 + ks * 32 + quad * 8);
      #pragma unroll
      for (int rt = 0; rt < RT; ++rt)
        acc[nt][rt] = __builtin_amdgcn_mfma_f32_16x16x32_bf16(a[rt], b, acc[nt][rt], 0, 0, 0);
    }
  }
}

// bias(+ReLU) store of D tiles to LDS; bias values are pre-hoisted registers (one per nt)
template<int NT, int RT, int DS>
__device__ __forceinline__ void store_relu(const f32x4 (&acc)[NT][RT], u16* dst,
    const int col0, const int rt0, const float* bias_r, const int lane)
{
  const int n = lane & 15, quad = lane >> 4;
  #pragma unroll
  for (int nt = 0; nt < NT; ++nt) {
    const float b = bias_r[nt];
    #pragma unroll
    for (int rt = 0; rt < RT; ++rt)
      #pragma unroll
      for (int i = 0; i < 4; ++i) {
        float v = fmaxf(acc[nt][rt][i] + b, 0.f);
        dst[((rt0 + rt) * 16 + quad * 4 + i) * DS + col0 + nt * 16 + n] = f2bf(v);
      }
  }
}

struct PrepArgs { const float* src[14]; int off[14]; int cnt[14]; };

__global__ void prep_weights(PrepArgs a, u16* __restrict__ dst) {
  const int j = blockIdx.y;
  const float* __restrict__ s = a.src[j];
  u16* d = dst + a.off[j];
  const int nel = a.cnt[j];
  for (int i = blockIdx.x * blockDim.x + threadIdx.x; i < nel; i += gridDim.x * blockDim.x)
    d[i] = f2bf(s[i]);
}

__global__ void zero_out_k(float* out) { if (threadIdx.x < 2) out[threadIdx.x] = 0.f; }

__global__ __launch_bounds__(NTHR, 2)
void vrnn_kernel(const float* __restrict__ states, const float* __restrict__ eps,
                 const float* __restrict__ enc_b1, const float* __restrict__ enc_b2,
                 const float* __restrict__ enc_mb, const float* __restrict__ enc_sb,
                 const float* __restrict__ pri_b1, const float* __restrict__ pri_b2,
                 const float* __restrict__ pri_mb, const float* __restrict__ pri_sb,
                 const float* __restrict__ dec_b1, const float* __restrict__ dec_b2,
                 const float* __restrict__ dec_mb, const float* __restrict__ dec_sb,
                 const float* __restrict__ gbih, const float* __restrict__ gbhh,
                 const u16* __restrict__ ws, float* __restrict__ out)
{
  __shared__ u16 cat[MROWS * CATS];   // [x|y|z|h] staging, bf16 (50.2 KB)
  __shared__ u16 hb1[MROWS * HBS];    // layer-1 outputs (33.8 KB)
  __shared__ u16 hb2[MROWS * HBS];    // layer-2 outputs (33.8 KB)

  const int tid = threadIdx.x;
  const int w = tid >> 6, lane = tid & 63;
  const int n = lane & 15, quad = lane >> 4;
  const int r0 = blockIdx.x * MROWS;
  const int n0 = w * 32;               // wave's 32-col strip for N=256 layers
  const int ctH = w & 3, rtH0 = (w >> 2) * 2;  // enc/pri heads: 16-col group, first of 2 row-tiles
  const int pD = w & 1, rtD = w >> 1;          // dec heads: 16-col group, single row-tile

  // ---- hoist all loop-invariant bias scalars into registers ----
  float b1e[2], b2e[2], b1p[2], b2p[2], b1d[2], b2d[2];
  float brg[2], bug[2], bing[2], bhng[2];
  #pragma unroll
  for (int nt = 0; nt < 2; ++nt) {
    const int j = n0 + nt * 16 + n;
    b1e[nt] = enc_b1[j]; b2e[nt] = enc_b2[j];
    b1p[nt] = pri_b1[j]; b2p[nt] = pri_b2[j];
    b1d[nt] = dec_b1[j]; b2d[nt] = dec_b2[j];
    brg[nt] = gbih[j] + gbhh[j];
    bug[nt] = gbih[RD + j] + gbhh[RD + j];
    bing[nt] = gbih[2 * RD + j];
    bhng[nt] = gbhh[2 * RD + j];
  }
  const int jH = ctH * 16 + n;
  const float bem = enc_mb[jH], bes = enc_sb[jH];
  const float bpm = pri_mb[jH], bps = pri_sb[jH];
  const int jD = pD * 16 + n;
  const float bdm = dec_mb[jD], bds = dec_sb[jD];

  // zero the h region of cat (h0 = 0)
  for (int i = tid; i < MROWS * (HD / 2); i += NTHR) {
    int row = i >> 7, c = (i & 127) * 2;
    *reinterpret_cast<u32*>(&cat[row * CATS + 128 + c]) = 0u;
  }

  float hreg[2][4][4];  // fp32 master h, C-layout
  #pragma unroll
  for (int a = 0; a < 2; ++a)
    #pragma unroll
    for (int b = 0; b < 4; ++b)
      #pragma unroll
      for (int c = 0; c < 4; ++c) hreg[a][b][c] = 0.f;

  // x/y staging map: each thread owns one float4 of x and one of y
  const int srow = tid >> 3, sc4 = (tid & 7) * 4;
  float4 xf = *reinterpret_cast<const float4*>(states + ((size_t)1 * BB + r0 + srow) * YD + sc4);
  float4 yf = *reinterpret_cast<const float4*>(states + ((size_t)0 * BB + r0 + srow) * YD + sc4);

  float kl_acc = 0.f, nll_acc = 0.f;

  for (int t = 0; t < TSTEPS; ++t) {
    // ---- write prefetched x=states[t+1], y=states[t] into cat ----
    {
      u16* dx = cat + srow * CATS + sc4;
      dx[0] = f2bf(xf.x); dx[1] = f2bf(xf.y); dx[2] = f2bf(xf.z); dx[3] = f2bf(xf.w);
      u16* dy = cat + srow * CATS + 32 + sc4;
      dy[0] = f2bf(yf.x); dy[1] = f2bf(yf.y); dy[2] = f2bf(yf.z); dy[3] = f2bf(yf.w);
    }
    __syncthreads();

    // ---- early-issue scalar prefetches consumed stages later ----
    float ev[2][4];
    #pragma unroll
    for (int rt = 0; rt < 2; ++rt)
      #pragma unroll
      for (int i = 0; i < 4; ++i)
        ev[rt][i] = eps[((size_t)t * BB + r0 + (rtH0 + rt) * 16 + quad * 4 + i) * ZD + jH];
    float xs[4];
    #pragma unroll
    for (int i = 0; i < 4; ++i)
      xs[i] = states[((size_t)(t + 1) * BB + r0 + rtD * 16 + quad * 4 + i) * YD + jD];

    // ---- enc layer 1: [x,y,h] (K=320) -> hb1 ----
    {
      f32x4 acc[2][4] = {};
      gemm_seg<2, 4, 2, CATS>(acc, ws + OFF_ENC_W1, 320, n0, 0, cat, 0, 0, lane);    // x,y
      gemm_seg<2, 4, 8, CATS>(acc, ws + OFF_ENC_W1, 320, n0, 64, cat, 128, 0, lane); // h
      store_relu<2, 4, HBS>(acc, hb1, n0, 0, b1e, lane);
    }
    __syncthreads();

    // ---- enc layer 2 -> hb2 ----
    {
      f32x4 acc[2][4] = {};
      gemm_seg<2, 4, 8, HBS>(acc, ws + OFF_ENC_W2, 256, n0, 0, hb1, 0, 0, lane);
      store_relu<2, 4, HBS>(acc, hb2, n0, 0, b2e, lane);
    }
    __syncthreads();

    // ---- enc heads (em, es) + z sample -> cat[z]; then pri layer 1 -> hb1 ----
    float emv[2][4], esv[2][4];
    {
      f32x4 am[1][2] = {}, as[1][2] = {};
      gemm_seg<1, 2, 8, HBS>(am, ws + OFF_ENC_H, 256, ctH * 16, 0, hb2, 0, rtH0, lane);
      gemm_seg<1, 2, 8, HBS>(as, ws + OFF_ENC_H, 256, 64 + ctH * 16, 0, hb2, 0, rtH0, lane);
      #pragma unroll
      for (int rt = 0; rt < 2; ++rt)
        #pragma unroll
        for (int i = 0; i < 4; ++i) {
          const int m = (rtH0 + rt) * 16 + quad * 4 + i;
          float em = am[0][rt][i] + bem;
          float es = softplus_f(as[0][rt][i] + bes);
          emv[rt][i] = em; esv[rt][i] = es;
          cat[m * CATS + 64 + jH] = f2bf(em + es * ev[rt][i]);
        }
      f32x4 acc[2][4] = {};
      gemm_seg<2, 4, 1, CATS>(acc, ws + OFF_PRI_W1, 288, n0, 0, cat, 32, 0, lane);   // y
      gemm_seg<2, 4, 8, CATS>(acc, ws + OFF_PRI_W1, 288, n0, 32, cat, 128, 0, lane); // h
      store_relu<2, 4, HBS>(acc, hb1, n0, 0, b1p, lane);
    }
    __syncthreads();

    // ---- pri layer 2 -> hb2 ----
    {
      f32x4 acc[2][4] = {};
      gemm_seg<2, 4, 8, HBS>(acc, ws + OFF_PRI_W2, 256, n0, 0, hb1, 0, 0, lane);
      store_relu<2, 4, HBS>(acc, hb2, n0, 0, b2p, lane);
    }
    __syncthreads();

    // ---- pri heads (pm, ps) + KL; then dec layer 1 ([y,z,h], K=352) -> hb1 ----
    {
      f32x4 am[1][2] = {}, as[1][2] = {};
      gemm_seg<1, 2, 8, HBS>(am, ws + OFF_PRI_H, 256, ctH * 16, 0, hb2, 0, rtH0, lane);
      gemm_seg<1, 2, 8, HBS>(as, ws + OFF_PRI_H, 256, 64 + ctH * 16, 0, hb2, 0, rtH0, lane);
      #pragma unroll
      for (int rt = 0; rt < 2; ++rt)
        #pragma unroll
        for (int i = 0; i < 4; ++i) {
          float pm = am[0][rt][i] + bpm;
          float ps = softplus_f(as[0][rt][i] + bps);
          float es = esv[rt][i], em = emv[rt][i];
          float d = em - pm;
          kl_acc += 0.5f * (2.f * __logf(ps * __builtin_amdgcn_rcpf(es))
                            + (es * es + d * d) / (ps * ps) - 1.f);
        }
      f32x4 acc[2][4] = {};
      gemm_seg<2, 4, 3, CATS>(acc, ws + OFF_DEC_W1, 352, n0, 0, cat, 32, 0, lane);   // y,z
      gemm_seg<2, 4, 8, CATS>(acc, ws + OFF_DEC_W1, 352, n0, 96, cat, 128, 0, lane); // h
      store_relu<2, 4, HBS>(acc, hb1, n0, 0, b1d, lane);
    }
    __syncthreads();

    // ---- dec layer 2 -> hb2 ----
    {
      f32x4 acc[2][4] = {};
      gemm_seg<2, 4, 8, HBS>(acc, ws + OFF_DEC_W2, 256, n0, 0, hb1, 0, 0, lane);
      store_relu<2, 4, HBS>(acc, hb2, n0, 0, b2d, lane);
    }
    __syncthreads();

    // ---- dec heads + NLL (all 8 waves); GRU staged GEMMs + gates ----
    {
      f32x4 am[1][1] = {}, as[1][1] = {};
      gemm_seg<1, 1, 8, HBS>(am, ws + OFF_DEC_H, 256, pD * 16, 0, hb2, 0, rtD, lane);
      gemm_seg<1, 1, 8, HBS>(as, ws + OFF_DEC_H, 256, 32 + pD * 16, 0, hb2, 0, rtD, lane);
      #pragma unroll
      for (int i = 0; i < 4; ++i) {
        float dm = am[0][0][i] + bdm;
        float ds = softplus_f(as[0][0][i] + bds);
        float dd = xs[i] - dm;
        nll_acc += __logf(ds) + dd * dd / (2.f * ds * ds) + 0.91893853320467274178f;
      }
      // GRU (torch gate order r,z,n), staged to bound register pressure:
      // aH = h@Whh_n; aR = [x,z]@Wih_r + h@Whh_r; aH := sigmoid(aR+br)*(aH+bhn)
      // aN = [x,z]@Wih_n; n = tanh(aN+bin+aH); aU = [x,z]@Wih_z + h@Whh_z
      f32x4 aH[2][4] = {};
      gemm_seg<2, 4, 8, CATS>(aH, ws + OFF_GWHH, 256, 2 * RD + n0, 0, cat, 128, 0, lane);
      {
        f32x4 aR[2][4] = {};
        gemm_seg<2, 4, 1, CATS>(aR, ws + OFF_GWIH, 96, n0, 0, cat, 0, 0, lane);
        gemm_seg<2, 4, 2, CATS>(aR, ws + OFF_GWIH, 96, n0, 32, cat, 64, 0, lane);
        gemm_seg<2, 4, 8, CATS>(aR, ws + OFF_GWHH, 256, n0, 0, cat, 128, 0, lane);
        #pragma unroll
        for (int nt = 0; nt < 2; ++nt)
          #pragma unroll
          for (int rt = 0; rt < 4; ++rt)
            #pragma unroll
            for (int i = 0; i < 4; ++i)
              aH[nt][rt][i] = sigmoid_f(aR[nt][rt][i] + brg[nt]) * (aH[nt][rt][i] + bhng[nt]);
      }
      {
        f32x4 aN[2][4] = {};
        gemm_seg<2, 4, 1, CATS>(aN, ws + OFF_GWIH, 96, 2 * RD + n0, 0, cat, 0, 0, lane);
        gemm_seg<2, 4, 2, CATS>(aN, ws + OFF_GWIH, 96, 2 * RD + n0, 32, cat, 64, 0, lane);
        #pragma unroll
        for (int nt = 0; nt < 2; ++nt)
          #pragma unroll
          for (int rt = 0; rt < 4; ++rt)
            #pragma unroll
            for (int i = 0; i < 4; ++i)
              aH[nt][rt][i] = tanh_f(aN[nt][rt][i] + bing[nt] + aH[nt][rt][i]);  // aH now holds n
      }
      {
        f32x4 aU[2][4] = {};
        gemm_seg<2, 4, 1, CATS>(aU, ws + OFF_GWIH, 96, RD + n0, 0, cat, 0, 0, lane);
        gemm_seg<2, 4, 2, CATS>(aU, ws + OFF_GWIH, 96, RD + n0, 32, cat, 64, 0, lane);
        gemm_seg<2, 4, 8, CATS>(aU, ws + OFF_GWHH, 256, RD + n0, 0, cat, 128, 0, lane);
        #pragma unroll
        for (int nt = 0; nt < 2; ++nt)
          #pragma unroll
          for (int rt = 0; rt < 4; ++rt)
            #pragma unroll
            for (int i = 0; i < 4; ++i) {
              float u = sigmoid_f(aU[nt][rt][i] + bug[nt]);
              hreg[nt][rt][i] = (1.f - u) * aH[nt][rt][i] + u * hreg[nt][rt][i];
            }
      }
      // prefetch next step's x,y while GRU math drains
      const int tn = (t + 1 < TSTEPS) ? t + 1 : TSTEPS - 1;
      xf = *reinterpret_cast<const float4*>(states + ((size_t)(tn + 1) * BB + r0 + srow) * YD + sc4);
      yf = *reinterpret_cast<const float4*>(states + ((size_t)tn * BB + r0 + srow) * YD + sc4);
    }
    __syncthreads();  // all reads of old cat-h/x/z complete before overwrite

    // ---- write h_new (bf16) back into cat[h] ----
    #pragma unroll
    for (int nt = 0; nt < 2; ++nt)
      #pragma unroll
      for (int rt = 0; rt < 4; ++rt)
        #pragma unroll
        for (int i = 0; i < 4; ++i)
          cat[(rt * 16 + quad * 4 + i) * CATS + 128 + n0 + nt * 16 + n] = f2bf(hreg[nt][rt][i]);
  }

  // ---- final reduction: wave shuffle + one atomic per wave ----
  float kv = kl_acc, nv = nll_acc;
  #pragma unroll
  for (int off = 32; off > 0; off >>= 1) {
    kv += __shfl_down(kv, off, 64);
    nv += __shfl_down(nv, off, 64);
  }
  if (lane == 0) {
    atomicAdd(out + 0, kv);
    atomicAdd(out + 1, nv);
  }
}

extern "C" void kernel_launch(void* const* d_in, const int* in_sizes, int n_in,
                              void* d_out, int out_size, void* d_ws, size_t ws_size,
                              hipStream_t stream) {
  const float* states = (const float*)d_in[0];
  const float* eps    = (const float*)d_in[1];
  u16* ws   = (u16*)d_ws;
  float* out = (float*)d_out;

  PrepArgs pa;
  const int jsrc[14] = {2, 4, 6, 8, 10, 12, 14, 16, 18, 20, 22, 24, 26, 27};
  const int joff[14] = {OFF_ENC_W1, OFF_ENC_W2, OFF_ENC_H, OFF_ENC_H + 16384,
                        OFF_PRI_W1, OFF_PRI_W2, OFF_PRI_H, OFF_PRI_H + 16384,
                        OFF_DEC_W1, OFF_DEC_W2, OFF_DEC_H, OFF_DEC_H + 8192,
                        OFF_GWIH, OFF_GWHH};
  const int jcnt[14] = {81920, 65536, 16384, 16384,
                        73728, 65536, 16384, 16384,
                        90112, 65536, 8192, 8192,
                        73728, 196608};
  for (int j = 0; j < 14; ++j) {
    pa.src[j] = (const float*)d_in[jsrc[j]];
    pa.off[j] = joff[j];
    pa.cnt[j] = jcnt[j];
  }

  zero_out_k<<<dim3(1), dim3(64), 0, stream>>>(out);
  prep_weights<<<dim3(64, 14), dim3(256), 0, stream>>>(pa, ws);
  vrnn_kernel<<<dim3(NBLK), dim3(NTHR), 0, stream>>>(
      states, eps,
      (const float*)d_in[3],  (const float*)d_in[5],
      (const float*)d_in[7],  (const float*)d_in[9],
      (const float*)d_in[11], (const float*)d_in[13],
      (const float*)d_in[15], (const float*)d_in[17],
      (const float*)d_in[19], (const float*)d_in[21],
      (const float*)d_in[23], (const float*)d_in[25],
      (const float*)d_in[28], (const float*)d_in[29],
      ws, out);
}

// Round 4
// 10772.610 us; speedup vs baseline: 1.3836x; 1.3836x over previous
//
#include <hip/hip_runtime.h>

typedef unsigned short u16;
typedef unsigned int u32;
typedef __bf16 bf16x8 __attribute__((ext_vector_type(8)));
typedef float f32x4 __attribute__((ext_vector_type(4)));

#define YD 32
#define ZD 64
#define HD 256
#define RD 256
#define TSTEPS 199   // T-1 scan steps
#define BB 2048
#define MROWS 32     // batch rows per block
#define NBLK 64      // 2048/32
#define NTHR 1024    // 16 waves
#define CATS 392     // [x(32)|y(32)|z(64)|h(256)] = 384 + 8 pad
#define HBS  264     // 256 + 8 pad
#define HES  136     // head buf enc/pri: [m|s](128) + 8 pad
#define HDS  72      // head buf dec: [dm|ds](64) + 8 pad

// bf16 weight layout offsets inside d_ws (element units, (N,K) row-major, K contiguous)
enum : int {
  OFF_ENC_W1 = 0,        // 256x320
  OFF_ENC_W2 = 81920,    // 256x256
  OFF_ENC_H  = 147456,   // [enc_mw;enc_sw] 128x256
  OFF_PRI_W1 = 180224,   // 256x288
  OFF_PRI_W2 = 253952,   // 256x256
  OFF_PRI_H  = 319488,   // [pri_mw;pri_sw] 128x256
  OFF_DEC_W1 = 352256,   // 256x352
  OFF_DEC_W2 = 442368,   // 256x256
  OFF_DEC_H  = 507904,   // [dec_mw;dec_sw] 64x256
  OFF_GWIH   = 524288,   // 768x96
  OFF_GWHH   = 598016,   // 768x256
};

__device__ __forceinline__ u16 f2bf(float f) {
  u32 u = __float_as_uint(f);
  u += 0x7fffu + ((u >> 16) & 1u);   // RTNE
  return (u16)(u >> 16);
}
__device__ __forceinline__ float bf2f(u16 b) {
  return __uint_as_float((u32)b << 16);
}
__device__ __forceinline__ float softplus_f(float x) {
  float l = __logf(1.f + __expf(-fabsf(x)));
  return x > 0.f ? x + l : l;
}
__device__ __forceinline__ float sigmoid_f(float x) {
  return __builtin_amdgcn_rcpf(1.f + __expf(-x));
}
__device__ __forceinline__ float tanh_f(float x) {
  float e = __expf(-2.f * fabsf(x));
  float t = (1.f - e) * __builtin_amdgcn_rcpf(1.f + e);
  return x >= 0.f ? t : -t;
}

// Wave-level GEMM over one contiguous K-segment, BATCHED LOADS:
// all KS x NT B-fragments are loaded into registers first (one base addr +
// immediate offsets -> back-to-back global_load_dwordx4), then the MFMA loop.
// A (LDS, row-major, stride AS): rows (rt0+rt)*16+(lane&15), cols acol0+ks*32+quad*8
// W (global bf16, (N,Kw) row-major): rows wrow0+nt*16+(lane&15), cols wk0+ks*32+quad*8
// D[m][n] += sum_k A[m][k]*W[n][k]  (act @ W.T)
template<int NT, int RT, int KS, int AS>
__device__ __forceinline__ void gemm_seg(f32x4 (&acc)[NT][RT],
    const u16* __restrict__ W, const int Kw, const int wrow0, const int wk0,
    const u16* A, const int acol0, const int rt0, const int lane)
{
  const int n = lane & 15, quad = lane >> 4;
  bf16x8 b[KS][NT];
  #pragma unroll
  for (int nt = 0; nt < NT; ++nt) {
    const u16* wp = W + (size_t)(wrow0 + nt * 16 + n) * Kw + wk0 + quad * 8;
    #pragma unroll
    for (int ks = 0; ks < KS; ++ks)
      b[ks][nt] = *reinterpret_cast<const bf16x8*>(wp + ks * 32);
  }
  #pragma unroll
  for (int ks = 0; ks < KS; ++ks) {
    bf16x8 a[RT];
    #pragma unroll
    for (int rt = 0; rt < RT; ++rt)
      a[rt] = *reinterpret_cast<const bf16x8*>(A + ((rt0 + rt) * 16 + n) * AS + acol0 + ks * 32 + quad * 8);
    #pragma unroll
    for (int nt = 0; nt < NT; ++nt)
      #pragma unroll
      for (int rt = 0; rt < RT; ++rt)
        acc[nt][rt] = __builtin_amdgcn_mfma_f32_16x16x32_bf16(a[rt], b[ks][nt], acc[nt][rt], 0, 0, 0);
  }
}

// bias + ReLU + bf16 store of D tile to LDS (NT=1)
template<int RT, int DS>
__device__ __forceinline__ void store_relu(const f32x4 (&acc)[1][RT], u16* dst,
    const int col0, const int rt0, const float bias, const int lane)
{
  const int n = lane & 15, quad = lane >> 4;
  #pragma unroll
  for (int rt = 0; rt < RT; ++rt)
    #pragma unroll
    for (int i = 0; i < 4; ++i) {
      float v = fmaxf(acc[0][rt][i] + bias, 0.f);
      dst[((rt0 + rt) * 16 + quad * 4 + i) * DS + col0 + n] = f2bf(v);
    }
}

struct PrepArgs { const float* src[14]; int off[14]; int cnt[14]; };

__global__ void prep_weights(PrepArgs a, u16* __restrict__ dst) {
  const int j = blockIdx.y;
  const float* __restrict__ s = a.src[j];
  u16* d = dst + a.off[j];
  const int nel = a.cnt[j];
  for (int i = blockIdx.x * blockDim.x + threadIdx.x; i < nel; i += gridDim.x * blockDim.x)
    d[i] = f2bf(s[i]);
}

__global__ void zero_out_k(float* out) { if (threadIdx.x < 2) out[threadIdx.x] = 0.f; }

__global__ __launch_bounds__(NTHR, 4)
void vrnn_kernel(const float* __restrict__ states, const float* __restrict__ eps,
                 const float* __restrict__ enc_b1, const float* __restrict__ enc_b2,
                 const float* __restrict__ enc_mb, const float* __restrict__ enc_sb,
                 const float* __restrict__ pri_b1, const float* __restrict__ pri_b2,
                 const float* __restrict__ pri_mb, const float* __restrict__ pri_sb,
                 const float* __restrict__ dec_b1, const float* __restrict__ dec_b2,
                 const float* __restrict__ dec_mb, const float* __restrict__ dec_sb,
                 const float* __restrict__ gbih, const float* __restrict__ gbhh,
                 const u16* __restrict__ ws, float* __restrict__ out)
{
  __shared__ u16 cat[MROWS * CATS];    // [x|y|z|h] staging (24.5 KB)
  __shared__ u16 hb1[MROWS * HBS];     // layer-1 outputs (16.5 KB)
  __shared__ u16 hb2[MROWS * HBS];     // layer-2 outputs (16.5 KB)
  __shared__ u16 hbhE[MROWS * HES];    // enc heads [em|softplus(es)] (8.5 KB)
  __shared__ u16 hbhP[MROWS * HES];    // pri heads [pm|softplus(ps)] (8.5 KB)
  __shared__ u16 hbhD[MROWS * HDS];    // dec heads [dm|softplus(ds)] (4.5 KB)

  const int tid = threadIdx.x;
  const int w = tid >> 6, lane = tid & 63;
  const int n = lane & 15, quad = lane >> 4;
  const int r0 = blockIdx.x * MROWS;
  const int n0 = w * 16;                       // wave's 16-col strip for N=256 layers
  const int cgE = w & 7, rtE = w >> 3;         // enc/pri heads: 8 col-groups x 2 row-tiles
  const int cgD = w & 3, rtD = (w >> 2) & 1;   // dec heads (waves 0-7): 4 cg x 2 rt

  // ---- hoist loop-invariant bias scalars ----
  const int jW = n0 + n;
  const float b1e = enc_b1[jW], b2e = enc_b2[jW];
  const float b1p = pri_b1[jW], b2p = pri_b2[jW];
  const float b1d = dec_b1[jW], b2d = dec_b2[jW];
  const float brg = gbih[jW] + gbhh[jW];
  const float bug = gbih[RD + jW] + gbhh[RD + jW];
  const float bing = gbih[2 * RD + jW];
  const float bhng = gbhh[2 * RD + jW];
  const float bhE = (cgE < 4) ? enc_mb[cgE * 16 + n] : enc_sb[(cgE - 4) * 16 + n];
  const float bhP = (cgE < 4) ? pri_mb[cgE * 16 + n] : pri_sb[(cgE - 4) * 16 + n];
  const float bhD = (cgD < 2) ? dec_mb[cgD * 16 + n] : dec_sb[(cgD - 2) * 16 + n];

  // zero the h region of cat (h0 = 0)
  for (int i = tid; i < MROWS * (HD / 2); i += NTHR) {
    int row = i >> 7, c = (i & 127) * 2;
    *reinterpret_cast<u32*>(&cat[row * CATS + 128 + c]) = 0u;
  }

  float hreg[2][4];  // fp32 master h (C-layout of wave's 16-col strip)
  #pragma unroll
  for (int a = 0; a < 2; ++a)
    #pragma unroll
    for (int c = 0; c < 4; ++c) hreg[a][c] = 0.f;

  // x/y staging: threads 0-255 own one float4 of x, 256-511 one of y
  const int srow = (tid & 255) >> 3, sc4 = (tid & 7) * 4;
  float4 xyf = make_float4(0.f, 0.f, 0.f, 0.f);
  if (tid < 512)
    xyf = *reinterpret_cast<const float4*>(states + ((size_t)((tid < 256) ? 1 : 0) * BB + r0 + srow) * YD + sc4);

  // element-parallel maps
  const int mz = tid >> 5, jz = (tid & 31) * 2;          // z/KL: 32x64 as float2
  const int mn = (tid & 511) >> 4, jn = (tid & 15) * 2;  // NLL: 32x32 as float2 (waves 0-7)

  float kl_acc = 0.f, nll_acc = 0.f;

  for (int t = 0; t < TSTEPS; ++t) {
    // ---- P0: write prefetched x=states[t+1], y=states[t] into cat; issue scalar prefetches ----
    if (tid < 512) {
      u16* d = cat + srow * CATS + ((tid < 256) ? 0 : 32) + sc4;
      d[0] = f2bf(xyf.x); d[1] = f2bf(xyf.y); d[2] = f2bf(xyf.z); d[3] = f2bf(xyf.w);
    }
    float2 ev2 = *reinterpret_cast<const float2*>(eps + ((size_t)t * BB + r0 + mz) * ZD + jz);
    float2 xs2 = make_float2(0.f, 0.f);
    if (tid < 512)
      xs2 = *reinterpret_cast<const float2*>(states + ((size_t)(t + 1) * BB + r0 + mn) * YD + jn);
    __syncthreads();

    // ---- P1: enc layer 1 [x,y,h] (K=320) -> hb1 ----
    {
      f32x4 acc[1][2] = {};
      gemm_seg<1, 2, 2, CATS>(acc, ws + OFF_ENC_W1, 320, n0, 0, cat, 0, 0, lane);    // x,y
      gemm_seg<1, 2, 8, CATS>(acc, ws + OFF_ENC_W1, 320, n0, 64, cat, 128, 0, lane); // h
      store_relu<2, HBS>(acc, hb1, n0, 0, b1e, lane);
    }
    __syncthreads();

    // ---- P2: enc layer 2 -> hb2 ----
    {
      f32x4 acc[1][2] = {};
      gemm_seg<1, 2, 8, HBS>(acc, ws + OFF_ENC_W2, 256, n0, 0, hb1, 0, 0, lane);
      store_relu<2, HBS>(acc, hb2, n0, 0, b2e, lane);
    }
    __syncthreads();

    // ---- P3: enc heads -> hbhE (raw em | softplus es) ----
    {
      f32x4 acc[1][1] = {};
      gemm_seg<1, 1, 8, HBS>(acc, ws + OFF_ENC_H, 256, cgE * 16, 0, hb2, 0, rtE, lane);
      #pragma unroll
      for (int i = 0; i < 4; ++i) {
        float v = acc[0][0][i] + bhE;
        if (cgE >= 4) v = softplus_f(v);
        hbhE[(rtE * 16 + quad * 4 + i) * HES + cgE * 16 + n] = f2bf(v);
      }
    }
    __syncthreads();

    // ---- P4: z sample -> cat[z] (all threads) + pri layer 1 [y,h] -> hb1 ----
    {
      float em0 = bf2f(hbhE[mz * HES + jz]);
      float em1 = bf2f(hbhE[mz * HES + jz + 1]);
      float es0 = bf2f(hbhE[mz * HES + 64 + jz]);
      float es1 = bf2f(hbhE[mz * HES + 64 + jz + 1]);
      cat[mz * CATS + 64 + jz] = f2bf(em0 + es0 * ev2.x);
      cat[mz * CATS + 64 + jz + 1] = f2bf(em1 + es1 * ev2.y);
      f32x4 acc[1][2] = {};
      gemm_seg<1, 2, 1, CATS>(acc, ws + OFF_PRI_W1, 288, n0, 0, cat, 32, 0, lane);   // y
      gemm_seg<1, 2, 8, CATS>(acc, ws + OFF_PRI_W1, 288, n0, 32, cat, 128, 0, lane); // h
      store_relu<2, HBS>(acc, hb1, n0, 0, b1p, lane);
    }
    __syncthreads();

    // ---- P5: pri layer 2 -> hb2 ----
    {
      f32x4 acc[1][2] = {};
      gemm_seg<1, 2, 8, HBS>(acc, ws + OFF_PRI_W2, 256, n0, 0, hb1, 0, 0, lane);
      store_relu<2, HBS>(acc, hb2, n0, 0, b2p, lane);
    }
    __syncthreads();

    // ---- P6: pri heads -> hbhP ----
    {
      f32x4 acc[1][1] = {};
      gemm_seg<1, 1, 8, HBS>(acc, ws + OFF_PRI_H, 256, cgE * 16, 0, hb2, 0, rtE, lane);
      #pragma unroll
      for (int i = 0; i < 4; ++i) {
        float v = acc[0][0][i] + bhP;
        if (cgE >= 4) v = softplus_f(v);
        hbhP[(rtE * 16 + quad * 4 + i) * HES + cgE * 16 + n] = f2bf(v);
      }
    }
    __syncthreads();

    // ---- P7: KL (all threads, element-parallel) + dec layer 1 [y,z,h] -> hb1 ----
    {
      #pragma unroll
      for (int c = 0; c < 2; ++c) {
        float em = bf2f(hbhE[mz * HES + jz + c]);
        float es = bf2f(hbhE[mz * HES + 64 + jz + c]);
        float pm = bf2f(hbhP[mz * HES + jz + c]);
        float ps = bf2f(hbhP[mz * HES + 64 + jz + c]);
        float d = em - pm;
        kl_acc += 0.5f * (2.f * __logf(ps * __builtin_amdgcn_rcpf(es))
                          + (es * es + d * d) / (ps * ps) - 1.f);
      }
      f32x4 acc[1][2] = {};
      gemm_seg<1, 2, 3, CATS>(acc, ws + OFF_DEC_W1, 352, n0, 0, cat, 32, 0, lane);   // y,z
      gemm_seg<1, 2, 8, CATS>(acc, ws + OFF_DEC_W1, 352, n0, 96, cat, 128, 0, lane); // h
      store_relu<2, HBS>(acc, hb1, n0, 0, b1d, lane);
    }
    __syncthreads();

    // ---- P8: dec layer 2 -> hb2 ----
    {
      f32x4 acc[1][2] = {};
      gemm_seg<1, 2, 8, HBS>(acc, ws + OFF_DEC_W2, 256, n0, 0, hb1, 0, 0, lane);
      store_relu<2, HBS>(acc, hb2, n0, 0, b2d, lane);
    }
    __syncthreads();

    // ---- P9: dec heads (waves 0-7) -> hbhD; GRU gemms + gates (all waves) ----
    {
      if (w < 8) {
        f32x4 acc[1][1] = {};
        gemm_seg<1, 1, 8, HBS>(acc, ws + OFF_DEC_H, 256, cgD * 16, 0, hb2, 0, rtD, lane);
        #pragma unroll
        for (int i = 0; i < 4; ++i) {
          float v = acc[0][0][i] + bhD;
          if (cgD >= 2) v = softplus_f(v);
          hbhD[(rtD * 16 + quad * 4 + i) * HDS + cgD * 16 + n] = f2bf(v);
        }
      }
      // GRU (torch gate order r,z,n), staged:
      f32x4 aH[1][2] = {};
      gemm_seg<1, 2, 8, CATS>(aH, ws + OFF_GWHH, 256, 2 * RD + n0, 0, cat, 128, 0, lane);
      {
        f32x4 aR[1][2] = {};
        gemm_seg<1, 2, 1, CATS>(aR, ws + OFF_GWIH, 96, n0, 0, cat, 0, 0, lane);       // x
        gemm_seg<1, 2, 2, CATS>(aR, ws + OFF_GWIH, 96, n0, 32, cat, 64, 0, lane);     // z
        gemm_seg<1, 2, 8, CATS>(aR, ws + OFF_GWHH, 256, n0, 0, cat, 128, 0, lane);    // h
        #pragma unroll
        for (int rt = 0; rt < 2; ++rt)
          #pragma unroll
          for (int i = 0; i < 4; ++i)
            aH[0][rt][i] = sigmoid_f(aR[0][rt][i] + brg) * (aH[0][rt][i] + bhng);
      }
      {
        f32x4 aN[1][2] = {};
        gemm_seg<1, 2, 1, CATS>(aN, ws + OFF_GWIH, 96, 2 * RD + n0, 0, cat, 0, 0, lane);
        gemm_seg<1, 2, 2, CATS>(aN, ws + OFF_GWIH, 96, 2 * RD + n0, 32, cat, 64, 0, lane);
        #pragma unroll
        for (int rt = 0; rt < 2; ++rt)
          #pragma unroll
          for (int i = 0; i < 4; ++i)
            aH[0][rt][i] = tanh_f(aN[0][rt][i] + bing + aH[0][rt][i]);  // aH now holds n
      }
      {
        f32x4 aU[1][2] = {};
        gemm_seg<1, 2, 1, CATS>(aU, ws + OFF_GWIH, 96, RD + n0, 0, cat, 0, 0, lane);
        gemm_seg<1, 2, 2, CATS>(aU, ws + OFF_GWIH, 96, RD + n0, 32, cat, 64, 0, lane);
        gemm_seg<1, 2, 8, CATS>(aU, ws + OFF_GWHH, 256, RD + n0, 0, cat, 128, 0, lane);
        #pragma unroll
        for (int rt = 0; rt < 2; ++rt)
          #pragma unroll
          for (int i = 0; i < 4; ++i) {
            float u = sigmoid_f(aU[0][rt][i] + bug);
            hreg[rt][i] = (1.f - u) * aH[0][rt][i] + u * hreg[rt][i];
          }
      }
      // prefetch next step's x/y float4
      const int tn = (t + 1 < TSTEPS) ? t + 1 : TSTEPS - 1;
      if (tid < 512)
        xyf = *reinterpret_cast<const float4*>(states + ((size_t)((tid < 256) ? tn + 1 : tn) * BB + r0 + srow) * YD + sc4);
    }
    __syncthreads();

    // ---- P10: NLL (waves 0-7, element-parallel) + write h_new -> cat[h] (all waves) ----
    if (tid < 512) {
      #pragma unroll
      for (int c = 0; c < 2; ++c) {
        float dm = bf2f(hbhD[mn * HDS + jn + c]);
        float ds = bf2f(hbhD[mn * HDS + 32 + jn + c]);
        float xv = (c == 0) ? xs2.x : xs2.y;
        float dd = xv - dm;
        nll_acc += __logf(ds) + dd * dd / (2.f * ds * ds) + 0.91893853320467274178f;
      }
    }
    #pragma unroll
    for (int rt = 0; rt < 2; ++rt)
      #pragma unroll
      for (int i = 0; i < 4; ++i)
        cat[(rt * 16 + quad * 4 + i) * CATS + 128 + n0 + n] = f2bf(hreg[rt][i]);
    // no barrier: P0 writes disjoint cat regions; P0's barrier orders h before enc1
  }

  // ---- final reduction: wave shuffle + one atomic per wave ----
  float kv = kl_acc, nv = nll_acc;
  #pragma unroll
  for (int off = 32; off > 0; off >>= 1) {
    kv += __shfl_down(kv, off, 64);
    nv += __shfl_down(nv, off, 64);
  }
  if (lane == 0) {
    atomicAdd(out + 0, kv);
    atomicAdd(out + 1, nv);
  }
}

extern "C" void kernel_launch(void* const* d_in, const int* in_sizes, int n_in,
                              void* d_out, int out_size, void* d_ws, size_t ws_size,
                              hipStream_t stream) {
  const float* states = (const float*)d_in[0];
  const float* eps    = (const float*)d_in[1];
  u16* ws   = (u16*)d_ws;
  float* out = (float*)d_out;

  PrepArgs pa;
  const int jsrc[14] = {2, 4, 6, 8, 10, 12, 14, 16, 18, 20, 22, 24, 26, 27};
  const int joff[14] = {OFF_ENC_W1, OFF_ENC_W2, OFF_ENC_H, OFF_ENC_H + 16384,
                        OFF_PRI_W1, OFF_PRI_W2, OFF_PRI_H, OFF_PRI_H + 16384,
                        OFF_DEC_W1, OFF_DEC_W2, OFF_DEC_H, OFF_DEC_H + 8192,
                        OFF_GWIH, OFF_GWHH};
  const int jcnt[14] = {81920, 65536, 16384, 16384,
                        73728, 65536, 16384, 16384,
                        90112, 65536, 8192, 8192,
                        73728, 196608};
  for (int j = 0; j < 14; ++j) {
    pa.src[j] = (const float*)d_in[jsrc[j]];
    pa.off[j] = joff[j];
    pa.cnt[j] = jcnt[j];
  }

  zero_out_k<<<dim3(1), dim3(64), 0, stream>>>(out);
  prep_weights<<<dim3(64, 14), dim3(256), 0, stream>>>(pa, ws);
  vrnn_kernel<<<dim3(NBLK), dim3(NTHR), 0, stream>>>(
      states, eps,
      (const float*)d_in[3],  (const float*)d_in[5],
      (const float*)d_in[7],  (const float*)d_in[9],
      (const float*)d_in[11], (const float*)d_in[13],
      (const float*)d_in[15], (const float*)d_in[17],
      (const float*)d_in[19], (const float*)d_in[21],
      (const float*)d_in[23], (const float*)d_in[25],
      (const float*)d_in[28], (const float*)d_in[29],
      ws, out);
}